// Round 5
// baseline (47.295 us; speedup 1.0000x reference)
//
#include <hip/hip_runtime.h>
#include <math.h>
#include <type_traits>

#define QDEPTH 10
#define WIRES 10
#define NSTATE 1024
#define NGATES (QDEPTH * WIRES)

// ---------------------------------------------------------------------------
// Layout: stored index s = w<<8 | j<<6 | lane  (w: 2 wave bits, j: 2 reg bits,
// lane: 6 bits). Wire q <-> bit (9-q):
//   wires 0,1 -> wave bits 9,8  (folded into the per-layer CNOT gather)
//   wires 2,3 -> reg bits 7,6   (pure-FMA register gates)
//   wires 4-9 -> lane bits 5..0 (shfl_xor gates)
// Per-layer CNOT chain: new[s] = old[G_l(s)], G_l GF(2)-linear.
// LDS word swizzle swz(x) = x ^ ((x>>5)&31); write side <=2-way (free).
// ---------------------------------------------------------------------------
constexpr unsigned sigma_apply(int q, int r, unsigned i) {
    int cb = 9 - q, tb = 9 - ((q + r) % 10);
    return i ^ (((i >> cb) & 1u) << tb);
}
constexpr unsigned G_apply(int l, unsigned i) {
    int r = (l % 9) + 1;
    for (int q = 9; q >= 0; --q) i = sigma_apply(q, r, i);  // G = s0∘s1∘…∘s9
    return i;
}
constexpr unsigned swz(unsigned w) { return w ^ ((w >> 5) & 31u); }

struct PermT { unsigned short t[QDEPTH][NSTATE]; };
constexpr PermT make_perm() {
    PermT p{};
    for (int l = 0; l < QDEPTH; ++l)
        for (unsigned s = 0; s < NSTATE; ++s)
            p.t[l][s] = (unsigned short)swz(G_apply(l, s));  // bits 8,9 preserved
    return p;
}
__constant__ PermT PERM = make_perm();

template <int N, int I = 0, typename F>
__device__ __forceinline__ void static_for(F&& f) {
    if constexpr (I < N) {
        f(std::integral_constant<int, I>{});
        static_for<N, I + 1>(f);
    }
}

// ---------------------------------------------------------------------------
// Kernel 1: 100 Rot gates; SU(2) so only (g00r,g00i,g01r,g01i) per gate.
// ---------------------------------------------------------------------------
__global__ void gates_kernel(const float* __restrict__ w, float* __restrict__ g) {
    int i = threadIdx.x;
    if (i >= NGATES) return;
    float phi = tanhf(w[3 * i + 0]);
    float th  = tanhf(w[3 * i + 1]);
    float om  = tanhf(w[3 * i + 2]);
    float c = cosf(0.5f * th), s = sinf(0.5f * th);
    float a = 0.5f * (phi + om), d = 0.5f * (phi - om);
    float* p = g + 4 * i;
    p[0] =  cosf(a) * c;   // g00r
    p[1] = -sinf(a) * c;   // g00i
    p[2] = -cosf(d) * s;   // g01r
    p[3] = -sinf(d) * s;   // g01i
}

// Gate on register bit JB of a 4-register state: 2 static pairs, pure FMA.
template <int JB>
__device__ __forceinline__ void apply_gate(float (&sr)[4], float (&si)[4],
                                           const float* __restrict__ gp) {
    const float Ar = gp[0], Ai = gp[1], Br = gp[2], Bi = gp[3];
    static_for<2>([&](auto P) {
        constexpr int p  = P.value;
        constexpr int lo = p & ((1 << JB) - 1);
        constexpr int j  = ((p & ~((1 << JB) - 1)) << 1) | lo;
        constexpr int jp = j | (1 << JB);
        float ar = sr[j], ai = si[j], br = sr[jp], bi = si[jp];
        sr[j]  = fmaf(Ar, ar, fmaf(-Ai, ai, fmaf(Br, br, -Bi * bi)));
        si[j]  = fmaf(Ar, ai, fmaf( Ai, ar, fmaf(Br, bi,  Bi * br)));
        sr[jp] = fmaf(-Br, ar, fmaf(-Bi, ai, fmaf(Ar, br,  Ai * bi)));
        si[jp] = fmaf(-Br, ai, fmaf( Bi, ar, fmaf(Ar, bi, -Ai * br)));
    });
}

// ---------------------------------------------------------------------------
// Kernel 2: 4 waves per batch element (256 thr); 4 complex amps per thread.
// One barrier + one LDS round-trip per layer (double-buffered); gates in LDS.
// ---------------------------------------------------------------------------
__global__ __launch_bounds__(256) void sim_kernel(const float* __restrict__ x,
                                                  const float* __restrict__ gates,
                                                  float* __restrict__ out) {
    __shared__ float lds[2][2048];     // [buf][0..1023]=re, [1024..2047]=im
    __shared__ float glds[NGATES * 4]; // all gate coeffs (broadcast reads)
    __shared__ float wsum[4];
    const int b    = blockIdx.x;
    const int tid  = threadIdx.x;
    const int w    = tid >> 6;         // 2 wave bits (wires 0,1)
    const int lane = tid & 63;
    const int whi  = w << 8;
    const float* xb = x + (size_t)b * NSTATE;

    float sr[4], si[4];

    // ---- stage gate table into LDS (once) ----
    for (int i = tid; i < NGATES * 4; i += 256) glds[i] = gates[i];

    // ---- amplitude embedding + cross-wave L2 normalize ----
    float ss = 0.f;
    static_for<4>([&](auto J) {
        constexpr int j = J.value;
        float v = xb[whi | (j << 6) | lane];
        sr[j] = v; si[j] = 0.f;
        ss = fmaf(v, v, ss);
    });
#pragma unroll
    for (int off = 1; off < 64; off <<= 1) ss += __shfl_xor(ss, off);
    if (lane == 0) wsum[w] = ss;
    __syncthreads();
    const float nrm = 1.0f / sqrtf(wsum[0] + wsum[1] + wsum[2] + wsum[3]);
    static_for<4>([&](auto J) { sr[J.value] *= nrm; });

#pragma unroll 1
    for (int l = 0; l < QDEPTH; ++l) {
        float* buf = lds[l & 1];
        const float* gl = glds + 40 * l;
        const unsigned short* pt = PERM.t[l];

        // prefetch gather addresses (hide latency under gate compute)
        int ta[4];
        static_for<4>([&](auto J) {
            constexpr int j = J.value;
            ta[j] = (int)pt[whi | (j << 6) | lane];
        });

        // ---- wires 2,3 on reg bits 1,0 (pure FMA) ----
        apply_gate<1>(sr, si, gl + 8);
        apply_gate<0>(sr, si, gl + 12);

        // ---- wires 4..9 on lane bits 5..0 (shuffles, no barrier) ----
        static_for<6>([&](auto Q) {
            constexpr int qq = Q.value;              // wire 4+qq
            constexpr int m  = 1 << (5 - qq);
            const float* gp = gl + 4 * (4 + qq);
            const float Ar = gp[0], Ai = gp[1], Br = gp[2], Bi = gp[3];
            const bool hi = (lane & m) != 0;
            const float Ais = hi ? -Ai : Ai;
            const float Brs = hi ? -Br : Br;
            static_for<4>([&](auto J) {
                constexpr int j = J.value;
                float pr = __shfl_xor(sr[j], m);
                float pi = __shfl_xor(si[j], m);
                float nr = fmaf(Ar, sr[j], fmaf(-Ais, si[j], fmaf(Brs, pr, -Bi * pi)));
                float ni = fmaf(Ar, si[j], fmaf( Ais, sr[j], fmaf(Brs, pi,  Bi * pr)));
                sr[j] = nr; si[j] = ni;
            });
        });

        // ---- write state to LDS (swizzled; <=2-way by construction) ----
        static_for<4>([&](auto J) {
            constexpr int j = J.value;
            int s = whi | (j << 6) | lane;
            int a = s ^ ((s >> 5) & 31);
            buf[a] = sr[j]; buf[a + 1024] = si[j];
        });
        __syncthreads();

        // ---- wires 0,1 (bits 9,8) folded into CNOT gather (4 partners) ----
        // U0 = wire0 gate (E,F), U1 = wire1 gate (C,D); rows by bits of g.
        const float Er = gl[0], Ei = gl[1], Fr = gl[2], Fi = gl[3];
        const float Cr = gl[4], Ci = gl[5], Dr = gl[6], Di = gl[7];
        static_for<4>([&](auto J) {
            constexpr int j = J.value;
            int t0 = ta[j];
            const bool h8 = (t0 & 256) != 0;
            const bool h9 = (t0 & 512) != 0;
            float Cis = h8 ? -Ci : Ci;
            float Drs = h8 ? -Dr : Dr;
            float Eis = h9 ? -Ei : Ei;
            float Frs = h9 ? -Fr : Fr;
            int t1 = t0 ^ 264, t2 = t0 ^ 528, t3 = t0 ^ 792;
            float v0r = buf[t0], v0i = buf[t0 + 1024];
            float v1r = buf[t1], v1i = buf[t1 + 1024];
            float v2r = buf[t2], v2i = buf[t2 + 1024];
            float v3r = buf[t3], v3i = buf[t3 + 1024];
            // inner (wire1) on both bit9 branches, row g8:
            float isr = fmaf(Cr, v0r, fmaf(-Cis, v0i, fmaf(Drs, v1r, -Di * v1i)));
            float isi = fmaf(Cr, v0i, fmaf( Cis, v0r, fmaf(Drs, v1i,  Di * v1r)));
            float ipr = fmaf(Cr, v2r, fmaf(-Cis, v2i, fmaf(Drs, v3r, -Di * v3i)));
            float ipi = fmaf(Cr, v2i, fmaf( Cis, v2r, fmaf(Drs, v3i,  Di * v3r)));
            // outer (wire0), row g9:
            sr[j] = fmaf(Er, isr, fmaf(-Eis, isi, fmaf(Frs, ipr, -Fi * ipi)));
            si[j] = fmaf(Er, isi, fmaf( Eis, isr, fmaf(Frs, ipi,  Fi * ipr)));
        });
        // no trailing barrier: next layer writes the other buffer
    }

    // ---- probs = clip(|amp|^2 * 1024, 0, 1); layout already logical ----
    float* ob = out + (size_t)b * NSTATE;
    static_for<4>([&](auto J) {
        constexpr int j = J.value;
        float p = fmaf(sr[j], sr[j], si[j] * si[j]) * (float)NSTATE;
        ob[whi | (j << 6) | lane] = fminf(p, 1.0f);
    });
}

extern "C" void kernel_launch(void* const* d_in, const int* in_sizes, int n_in,
                              void* d_out, int out_size, void* d_ws, size_t ws_size,
                              hipStream_t stream) {
    const float* x = (const float*)d_in[0];   // [1024,1,32,32] f32
    const float* w = (const float*)d_in[1];   // [10,10,3] f32
    float* out   = (float*)d_out;             // [1024,1,32,32] f32
    float* gates = (float*)d_ws;              // 100*4 floats scratch

    gates_kernel<<<1, 128, 0, stream>>>(w, gates);
    sim_kernel<<<1024, 256, 0, stream>>>(x, gates, out);
}